// Round 2
// baseline (128.944 us; speedup 1.0000x reference)
//
#include <hip/hip_runtime.h>
#include <hip/hip_bf16.h>
#include <stdint.h>

#define E_  1024
#define H_  16
#define D_  64
#define K_  8
#define B_  4
#define S_  2048
#define KH_ 128   // K_*H_

typedef __attribute__((ext_vector_type(8))) short   short8;
typedef __attribute__((ext_vector_type(8))) ushort  ushort8;
typedef __attribute__((ext_vector_type(4))) float   f32x4;

__device__ __forceinline__ ushort f2bf(float x){
  union { float f; uint32_t u; } v; v.f = x;
  return (ushort)((v.u + 0x7FFFu + ((v.u >> 16) & 1u)) >> 16);
}

// ------- F0: fused [t0: rep (B,S,E) f32 -> repT (B,E,S) bf16] + [k1: qs] --
__global__ __launch_bounds__(256) void f0_repT_qs(const float* __restrict__ rep,
                                                  ushort* __restrict__ repT,
                                                  const float* __restrict__ queries,
                                                  const float* __restrict__ Wq,
                                                  const float* __restrict__ bq,
                                                  float* __restrict__ qs){
  __shared__ ushort tile[64][65];
  int bid = blockIdx.x;
  int t = threadIdx.x;
  if (bid < 2048){
    // transpose: 64x64 tile
    int et = bid & 15;          // E/64
    int st = (bid >> 4) & 31;   // S/64
    int b  = bid >> 9;
    int s_l = t >> 2;
    int e0  = (t & 3) * 16;
    const float* src = rep + ((size_t)(b*S_) + st*64 + s_l)*E_ + et*64 + e0;
    #pragma unroll
    for (int q = 0; q < 4; q++){
      float4 v = *(const float4*)(src + q*4);
      tile[s_l][e0+q*4+0] = f2bf(v.x);
      tile[s_l][e0+q*4+1] = f2bf(v.y);
      tile[s_l][e0+q*4+2] = f2bf(v.z);
      tile[s_l][e0+q*4+3] = f2bf(v.w);
    }
    __syncthreads();
    int e_l = t >> 2;
    int sc  = (t & 3) * 16;
    alignas(16) ushort tmp[16];
    #pragma unroll
    for (int i = 0; i < 16; i++) tmp[i] = tile[sc+i][e_l];
    ushort* dst = repT + ((size_t)(b*E_) + et*64 + e_l)*S_ + st*64 + sc;
    *(uint4*)dst       = *(const uint4*)tmp;
    *(uint4*)(dst + 8) = *(const uint4*)(tmp + 8);
  } else {
    // qs[k,f] = (queries[k,:]·Wq[k,f,:] + bq)*0.125
    int gw = ((bid - 2048) * 256 + t) >> 6;
    int lane = t & 63;
    int k = gw >> 10, f = gw & 1023;
    const float* wrow = Wq + ((size_t)(k*E_) + f)*E_;
    const float* qrow = queries + k*E_;
    float acc = 0.f;
    #pragma unroll
    for (int j = 0; j < 4; j++){
      int e = (j*64 + lane)*4;
      float4 w = *(const float4*)(wrow + e);
      float4 q = *(const float4*)(qrow + e);
      acc += w.x*q.x + w.y*q.y + w.z*q.z + w.w*q.w;
    }
    #pragma unroll
    for (int off = 32; off; off >>= 1) acc += __shfl_down(acc, off);
    if (lane == 0) qs[k*E_ + f] = (acc + bq[k*E_ + f]) * 0.125f;
  }
}

// ---------------- K2: qk[k,h,e] (bf16) and qb[k,h] ------------------------
// grid 512: eq = bid&3 (256-e chunk), kh = bid>>2. 1 e per thread.
__global__ __launch_bounds__(256) void k2_qk(const float* __restrict__ qs,
                                             const float* __restrict__ Wk,
                                             const float* __restrict__ bk,
                                             ushort* __restrict__ qkb,
                                             float* __restrict__ qb){
  int bid = blockIdx.x;
  int eq = bid & 3;
  int kh = bid >> 2;
  int k = kh >> 4, h = kh & 15;
  __shared__ float qsh[64];
  int t = threadIdx.x;
  if (t < 64) qsh[t] = qs[k*E_ + h*64 + t];
  __syncthreads();
  int e = eq*256 + t;
  const float* wbase = Wk + ((size_t)(k*E_) + h*64)*E_ + e;
  float a = 0.f;
  #pragma unroll 8
  for (int d = 0; d < 64; d++) a += qsh[d] * wbase[(size_t)d*E_];
  qkb[kh*E_ + e] = f2bf(a);
  if (eq == 0 && t == 0){
    float s = 0.f;
    for (int d = 0; d < 64; d++) s += qsh[d] * bk[k*E_ + h*64 + d];
    qb[kh] = s;
  }
}

// ---------------- K3: scores[b,kh,s] = rep·qk + qb + mask (MFMA, direct) --
// 256 blocks = b(4) x st(64 tiles of 32 s). 512 threads = 8 waves.
// Wave wv: kh tile [wv*16, wv*16+16), s tile [st*32, st*32+32). No LDS, no barriers.
__global__ __launch_bounds__(512) void k3_scores(const float* __restrict__ rep,
                                                 const ushort* __restrict__ qkb,
                                                 const float* __restrict__ qb,
                                                 const float* __restrict__ mask,
                                                 float* __restrict__ scores){
  int bid = blockIdx.x;
  int st = bid & 63;
  int b  = bid >> 6;
  int t = threadIdx.x, wv = t >> 6, lane = t & 63;
  int r0 = lane & 15, r1 = lane >> 4;     // frag row, k-group
  const float*  Abase = rep + ((size_t)(b*S_) + st*32)*E_;
  const ushort* Bbase = qkb + ((size_t)(wv*16) + r0)*E_;
  f32x4 acc[2];
  acc[0] = (f32x4){0.f,0.f,0.f,0.f};
  acc[1] = (f32x4){0.f,0.f,0.f,0.f};
  for (int ke = 0; ke < 32; ke++){
    int kc = ke*32 + r1*8;
    short8 bf = *(const short8*)(Bbase + kc);
    #pragma unroll
    for (int mt = 0; mt < 2; mt++){
      const float* ap = Abase + ((size_t)(mt*16) + r0)*E_ + kc;
      float4 v0 = *(const float4*)ap;
      float4 v1 = *(const float4*)(ap + 4);
      ushort8 u;
      u[0]=f2bf(v0.x); u[1]=f2bf(v0.y); u[2]=f2bf(v0.z); u[3]=f2bf(v0.w);
      u[4]=f2bf(v1.x); u[5]=f2bf(v1.y); u[6]=f2bf(v1.z); u[7]=f2bf(v1.w);
      short8 af = (short8)u;
      acc[mt] = __builtin_amdgcn_mfma_f32_16x16x32_bf16(af, bf, acc[mt], 0,0,0);
    }
  }
  // epilogue: D[m=s_local, n=kh_local]: col=lane&15 -> kh, row=(lane>>4)*4+r -> s
  int kh = wv*16 + r0;
  float qbv = qb[kh];
  #pragma unroll
  for (int mt = 0; mt < 2; mt++){
    int s0 = st*32 + mt*16 + r1*4;
    float4 m = *(const float4*)(mask + b*S_ + s0);
    float4 o;
    o.x = acc[mt][0] + qbv + m.x;
    o.y = acc[mt][1] + qbv + m.y;
    o.z = acc[mt][2] + qbv + m.z;
    o.w = acc[mt][3] + qbv + m.w;
    *(float4*)(scores + ((size_t)(b*KH_) + kh)*S_ + s0) = o;
  }
}

// ---------------- K4: row softmax -> probs bf16 ---------------------------
__global__ __launch_bounds__(256) void k4_softmax(const float* __restrict__ scores,
                                                  ushort* __restrict__ probs){
  __shared__ float red[4];
  int row = blockIdx.x;
  int t = threadIdx.x, wv = t >> 6, lane = t & 63;
  const float* x = scores + (size_t)row * S_;
  float v[8];
  *(float4*)(v)   = *(const float4*)(x + t*8);
  *(float4*)(v+4) = *(const float4*)(x + t*8 + 4);
  float m = v[0];
  #pragma unroll
  for (int i = 1; i < 8; i++) m = fmaxf(m, v[i]);
  #pragma unroll
  for (int off = 32; off; off >>= 1) m = fmaxf(m, __shfl_down(m, off));
  if (lane == 0) red[wv] = m;
  __syncthreads();
  float M = fmaxf(fmaxf(red[0], red[1]), fmaxf(red[2], red[3]));
  __syncthreads();
  float s = 0.f;
  #pragma unroll
  for (int i = 0; i < 8; i++){ v[i] = __expf(v[i] - M); s += v[i]; }
  #pragma unroll
  for (int off = 32; off; off >>= 1) s += __shfl_down(s, off);
  if (lane == 0) red[wv] = s;
  __syncthreads();
  float inv = 1.0f / (red[0] + red[1] + red[2] + red[3]);
  ushort8 o;
  #pragma unroll
  for (int i = 0; i < 8; i++) o[i] = f2bf(v[i] * inv);
  *(ushort8*)(probs + (size_t)row*S_ + t*8) = o;
}

// ---------------- K5: wrepP[sh][b,kh,e] partial = probs·rep (MFMA) --------
// grid 1024: khh=bid&1, sh=(bid>>1)&1, b=(bid>>2)&3, et=bid>>4. 4 waves.
// Wave: 16 kh x 16 e, K = 1024 (one S half), 32 iters, 1 MFMA/iter.
__global__ __launch_bounds__(256) void k5_wrep(const ushort* __restrict__ probs,
                                               const ushort* __restrict__ repT,
                                               float* __restrict__ wrepP){
  int bid = blockIdx.x;
  int khh = bid & 1, sh = (bid >> 1) & 1, b = (bid >> 2) & 3, et = bid >> 4;
  int t = threadIdx.x, wv = t >> 6, lane = t & 63;
  int r0 = lane & 15, r1 = lane >> 4;
  const ushort* Ap = probs + ((size_t)(b*KH_) + khh*64 + wv*16 + r0)*S_ + sh*1024 + r1*8;
  const ushort* Bp = repT  + ((size_t)(b*E_) + et*16 + r0)*S_ + sh*1024 + r1*8;
  f32x4 c = (f32x4){0.f,0.f,0.f,0.f};
  for (int ks = 0; ks < 32; ks++){
    short8 a  = *(const short8*)(Ap + ks*32);
    short8 bb = *(const short8*)(Bp + ks*32);
    c = __builtin_amdgcn_mfma_f32_16x16x32_bf16(a, bb, c, 0,0,0);
  }
  int kh_out = khh*64 + wv*16 + r1*4;
  float* outp = wrepP + (size_t)sh*(B_*KH_*E_)
              + ((size_t)(b*KH_) + kh_out)*E_ + et*16 + r0;
  #pragma unroll
  for (int r = 0; r < 4; r++) outp[(size_t)r*E_] = c[r];
}

// ---------------- K6: ctx[k,b,f] = (wrepP0+wrepP1)[b,kh(f),:]·Wv[k,f,:]+bv
__global__ __launch_bounds__(256) void k6_ctx(const float* __restrict__ wrepP,
                                              const float* __restrict__ Wv,
                                              const float* __restrict__ bv,
                                              float* __restrict__ ctx){
  int gw = (blockIdx.x*256 + threadIdx.x) >> 6;
  int lane = threadIdx.x & 63;
  int k = gw >> 10, f = gw & 1023;
  int h = f >> 6;
  const float* wrow = Wv + ((size_t)(k*E_) + f)*E_;
  const size_t shs = (size_t)B_*KH_*E_;
  float a0=0.f, a1=0.f, a2=0.f, a3=0.f;
  #pragma unroll
  for (int j = 0; j < 4; j++){
    int e = (j*64 + lane)*4;
    float4 w = *(const float4*)(wrow + e);
    #pragma unroll
    for (int b = 0; b < 4; b++){
      const float* xr = wrepP + ((size_t)(b*KH_) + k*16 + h)*E_ + e;
      float4 p0 = *(const float4*)xr;
      float4 p1 = *(const float4*)(xr + shs);
      float s = w.x*(p0.x+p1.x) + w.y*(p0.y+p1.y) + w.z*(p0.z+p1.z) + w.w*(p0.w+p1.w);
      if (b == 0) a0 += s; else if (b == 1) a1 += s; else if (b == 2) a2 += s; else a3 += s;
    }
  }
  #pragma unroll
  for (int off = 32; off; off >>= 1){
    a0 += __shfl_down(a0, off); a1 += __shfl_down(a1, off);
    a2 += __shfl_down(a2, off); a3 += __shfl_down(a3, off);
  }
  if (lane == 0){
    float bvv = bv[k*E_ + f];
    ctx[((size_t)(k*B_) + 0)*E_ + f] = a0 + bvv;
    ctx[((size_t)(k*B_) + 1)*E_ + f] = a1 + bvv;
    ctx[((size_t)(k*B_) + 2)*E_ + f] = a2 + bvv;
    ctx[((size_t)(k*B_) + 3)*E_ + f] = a3 + bvv;
  }
}

// ---------------- K7/K8: out[(k,b),f] = in[(k,b),:]·W[k,f,:] + bias -------
__global__ __launch_bounds__(256) void gemv_kb(const float* __restrict__ in,
                                               const float* __restrict__ W,
                                               const float* __restrict__ bias,
                                               float* __restrict__ outp){
  int gw = (blockIdx.x*256 + threadIdx.x) >> 6;
  int lane = threadIdx.x & 63;
  int k = gw >> 10, f = gw & 1023;
  const float* wrow = W + ((size_t)(k*E_) + f)*E_;
  const float* x0 = in + ((size_t)(k*B_) + 0)*E_;
  const float* x1 = in + ((size_t)(k*B_) + 1)*E_;
  const float* x2 = in + ((size_t)(k*B_) + 2)*E_;
  const float* x3 = in + ((size_t)(k*B_) + 3)*E_;
  float a0=0.f, a1=0.f, a2=0.f, a3=0.f;
  #pragma unroll
  for (int j = 0; j < 4; j++){
    int e = (j*64 + lane)*4;
    float4 w = *(const float4*)(wrow + e);
    float4 p;
    p = *(const float4*)(x0+e); a0 += w.x*p.x + w.y*p.y + w.z*p.z + w.w*p.w;
    p = *(const float4*)(x1+e); a1 += w.x*p.x + w.y*p.y + w.z*p.z + w.w*p.w;
    p = *(const float4*)(x2+e); a2 += w.x*p.x + w.y*p.y + w.z*p.z + w.w*p.w;
    p = *(const float4*)(x3+e); a3 += w.x*p.x + w.y*p.y + w.z*p.z + w.w*p.w;
  }
  #pragma unroll
  for (int off = 32; off; off >>= 1){
    a0 += __shfl_down(a0, off); a1 += __shfl_down(a1, off);
    a2 += __shfl_down(a2, off); a3 += __shfl_down(a3, off);
  }
  if (lane == 0){
    float bb = bias[k*E_ + f];
    outp[((size_t)(k*B_) + 0)*E_ + f] = a0 + bb;
    outp[((size_t)(k*B_) + 1)*E_ + f] = a1 + bb;
    outp[((size_t)(k*B_) + 2)*E_ + f] = a2 + bb;
    outp[((size_t)(k*B_) + 3)*E_ + f] = a3 + bb;
  }
}

// ---------------- K9: LayerNorm over E, write d_out[b,k,e] ----------------
__global__ __launch_bounds__(256) void k9_ln(const float* __restrict__ outkb,
                                             const float* __restrict__ gamma,
                                             const float* __restrict__ beta,
                                             float* __restrict__ out){
  __shared__ float rs[4], rs2[4];
  int row = blockIdx.x;            // b*K_ + k
  int b = row >> 3, k = row & 7;
  int t = threadIdx.x, wv = t >> 6, lane = t & 63;
  const float* x = outkb + ((size_t)(k*B_) + b)*E_;
  float4 v = *(const float4*)(x + t*4);
  float s  = v.x + v.y + v.z + v.w;
  float s2 = v.x*v.x + v.y*v.y + v.z*v.z + v.w*v.w;
  #pragma unroll
  for (int off = 32; off; off >>= 1){ s += __shfl_down(s, off); s2 += __shfl_down(s2, off); }
  if (lane == 0){ rs[wv] = s; rs2[wv] = s2; }
  __syncthreads();
  float S  = rs[0] + rs[1] + rs[2] + rs[3];
  float S2 = rs2[0] + rs2[1] + rs2[2] + rs2[3];
  float mu = S * (1.0f/E_);
  float var = S2 * (1.0f/E_) - mu*mu;
  float inv = rsqrtf(var + 1e-5f);
  float4 g  = *(const float4*)(gamma + t*4);
  float4 bt = *(const float4*)(beta + t*4);
  float4 o;
  o.x = g.x*(v.x-mu)*inv + bt.x;
  o.y = g.y*(v.y-mu)*inv + bt.y;
  o.z = g.z*(v.z-mu)*inv + bt.z;
  o.w = g.w*(v.w-mu)*inv + bt.w;
  *(float4*)(out + ((size_t)(b*K_) + k)*E_ + t*4) = o;
}

extern "C" void kernel_launch(void* const* d_in, const int* in_sizes, int n_in,
                              void* d_out, int out_size, void* d_ws, size_t ws_size,
                              hipStream_t stream){
  const float* rep     = (const float*)d_in[0];
  const float* mask    = (const float*)d_in[1];
  const float* queries = (const float*)d_in[2];
  const float* Wq = (const float*)d_in[3];
  const float* bq = (const float*)d_in[4];
  const float* Wk = (const float*)d_in[5];
  const float* bk = (const float*)d_in[6];
  const float* Wv = (const float*)d_in[7];
  const float* bv = (const float*)d_in[8];
  const float* Wo = (const float*)d_in[9];
  const float* bo = (const float*)d_in[10];
  const float* Wp = (const float*)d_in[11];
  const float* bp = (const float*)d_in[12];
  const float* gamma = (const float*)d_in[13];
  const float* beta  = (const float*)d_in[14];
  float* out = (float*)d_out;

  char* ws = (char*)d_ws;
  size_t off = 0;
  ushort* repT  = (ushort*)(ws + off); off += (size_t)B_*E_*S_*2;      // 16 MB
  float*  qs    = (float*)(ws + off);  off += (size_t)K_*E_*4;         // 32 KB
  ushort* qkb   = (ushort*)(ws + off); off += (size_t)KH_*E_*2;        // 256 KB
  float*  qb    = (float*)(ws + off);  off += 1024;
  float*  scores= (float*)(ws + off);  off += (size_t)B_*KH_*S_*4;     // 4 MB
  ushort* probs = (ushort*)(ws + off); off += (size_t)B_*KH_*S_*2;     // 2 MB
  float*  wrepP = (float*)(ws + off);  off += (size_t)2*B_*KH_*E_*4;   // 4 MB
  float*  ctx   = (float*)(ws + off);  off += (size_t)K_*B_*E_*4;
  float*  attn  = (float*)(ws + off);  off += (size_t)K_*B_*E_*4;
  float*  outkb = (float*)(ws + off);  off += (size_t)K_*B_*E_*4;

  f0_repT_qs<<<4096, 256, 0, stream>>>(rep, repT, queries, Wq, bq, qs);
  k2_qk     <<<512,  256, 0, stream>>>(qs, Wk, bk, qkb, qb);
  k3_scores <<<256,  512, 0, stream>>>(rep, qkb, qb, mask, scores);
  k4_softmax<<<512,  256, 0, stream>>>(scores, probs);
  k5_wrep   <<<1024, 256, 0, stream>>>(probs, repT, wrepP);
  k6_ctx    <<<2048, 256, 0, stream>>>(wrepP, Wv, bv, ctx);
  gemv_kb   <<<2048, 256, 0, stream>>>(ctx, Wo, bo, attn);
  gemv_kb   <<<2048, 256, 0, stream>>>(attn, Wp, bp, outkb);
  k9_ln     <<<32,   256, 0, stream>>>(outkb, gamma, beta, out);
}

// Round 3
// 111.135 us; speedup vs baseline: 1.1602x; 1.1602x over previous
//
#include <hip/hip_runtime.h>
#include <hip/hip_bf16.h>
#include <stdint.h>

#define E_  1024
#define H_  16
#define D_  64
#define K_  8
#define B_  4
#define S_  2048
#define KH_ 128   // K_*H_

typedef __attribute__((ext_vector_type(8))) short   short8;
typedef __attribute__((ext_vector_type(8))) ushort  ushort8;
typedef __attribute__((ext_vector_type(4))) ushort  ushort4v;
typedef __attribute__((ext_vector_type(4))) float   f32x4;

__device__ __forceinline__ ushort f2bf(float x){
  union { float f; uint32_t u; } v; v.f = x;
  return (ushort)((v.u + 0x7FFFu + ((v.u >> 16) & 1u)) >> 16);
}

// ------- F0: fused [t0: rep (B,S,E) f32 -> repT (B,E,S) bf16] + [k1: qs] --
__global__ __launch_bounds__(256) void f0_repT_qs(const float* __restrict__ rep,
                                                  ushort* __restrict__ repT,
                                                  const float* __restrict__ queries,
                                                  const float* __restrict__ Wq,
                                                  const float* __restrict__ bq,
                                                  float* __restrict__ qs){
  __shared__ ushort tile[64][65];
  int bid = blockIdx.x;
  int t = threadIdx.x;
  if (bid < 2048){
    int et = bid & 15;          // E/64
    int st = (bid >> 4) & 31;   // S/64
    int b  = bid >> 9;
    int s_l = t >> 2;
    int e0  = (t & 3) * 16;
    const float* src = rep + ((size_t)(b*S_) + st*64 + s_l)*E_ + et*64 + e0;
    #pragma unroll
    for (int q = 0; q < 4; q++){
      float4 v = *(const float4*)(src + q*4);
      tile[s_l][e0+q*4+0] = f2bf(v.x);
      tile[s_l][e0+q*4+1] = f2bf(v.y);
      tile[s_l][e0+q*4+2] = f2bf(v.z);
      tile[s_l][e0+q*4+3] = f2bf(v.w);
    }
    __syncthreads();
    int e_l = t >> 2;
    int sc  = (t & 3) * 16;
    alignas(16) ushort tmp[16];
    #pragma unroll
    for (int i = 0; i < 16; i++) tmp[i] = tile[sc+i][e_l];
    ushort* dst = repT + ((size_t)(b*E_) + et*64 + e_l)*S_ + st*64 + sc;
    *(uint4*)dst       = *(const uint4*)tmp;
    *(uint4*)(dst + 8) = *(const uint4*)(tmp + 8);
  } else {
    int gw = ((bid - 2048) * 256 + t) >> 6;
    int lane = t & 63;
    int k = gw >> 10, f = gw & 1023;
    const float* wrow = Wq + ((size_t)(k*E_) + f)*E_;
    const float* qrow = queries + k*E_;
    float acc = 0.f;
    #pragma unroll
    for (int j = 0; j < 4; j++){
      int e = (j*64 + lane)*4;
      float4 w = *(const float4*)(wrow + e);
      float4 q = *(const float4*)(qrow + e);
      acc += w.x*q.x + w.y*q.y + w.z*q.z + w.w*q.w;
    }
    #pragma unroll
    for (int off = 32; off; off >>= 1) acc += __shfl_down(acc, off);
    if (lane == 0) qs[k*E_ + f] = (acc + bq[k*E_ + f]) * 0.125f;
  }
}

// ---------------- K2: qk[k,h,e] (bf16) and qb[k,h] ------------------------
__global__ __launch_bounds__(256) void k2_qk(const float* __restrict__ qs,
                                             const float* __restrict__ Wk,
                                             const float* __restrict__ bk,
                                             ushort* __restrict__ qkb,
                                             float* __restrict__ qb){
  int bid = blockIdx.x;
  int eq = bid & 3;
  int kh = bid >> 2;
  int k = kh >> 4, h = kh & 15;
  __shared__ float qsh[64];
  int t = threadIdx.x;
  if (t < 64) qsh[t] = qs[k*E_ + h*64 + t];
  __syncthreads();
  int e = eq*256 + t;
  const float* wbase = Wk + ((size_t)(k*E_) + h*64)*E_ + e;
  float a = 0.f;
  #pragma unroll 8
  for (int d = 0; d < 64; d++) a += qsh[d] * wbase[(size_t)d*E_];
  qkb[kh*E_ + e] = f2bf(a);
  if (eq == 0 && t == 0){
    float s = 0.f;
    for (int d = 0; d < 64; d++) s += qsh[d] * bk[k*E_ + h*64 + d];
    qb[kh] = s;
  }
}

// ---------------- K3: scores[b,kh,s] = rep·qk + qb + mask -----------------
// 512 blocks = b(4) x st(128 tiles of 16 s). 512 threads = 8 waves.
// LDS: double-buffered bf16 A-tile [16 s][128+8 k]. Depth-2 reg prefetch of
// the f32 staging loads; raw s_barrier (no vmcnt drain) keeps them in flight.
#define K3PAD 8
__global__ __launch_bounds__(512) void k3_scores(const float* __restrict__ rep,
                                                 const ushort* __restrict__ qkb,
                                                 const float* __restrict__ qb,
                                                 const float* __restrict__ mask,
                                                 float* __restrict__ scores){
  __shared__ ushort abuf[2][16][128 + K3PAD];
  int bid = blockIdx.x;
  int st = bid & 127;
  int b  = bid >> 7;
  int t = threadIdx.x, wv = t >> 6, lane = t & 63;
  int r0 = lane & 15, r1 = lane >> 4;
  // staging role: thread loads one float4 of the 16x128 f32 chunk
  int srow = t >> 5;           // 0..15
  int scol = (t & 31) * 4;     // 0..124
  const float* srcRow = rep + ((size_t)(b*S_) + st*16 + srow)*E_ + scol;
  const ushort* Bbase = qkb + ((size_t)(wv*16) + r0)*E_;
  f32x4 acc = (f32x4){0.f,0.f,0.f,0.f};

  // prologue: chunk0 + chunk1 loads in flight; write chunk0 to buf0
  float4 v0     = *(const float4*)(srcRow);
  float4 v_next = *(const float4*)(srcRow + 128);
  {
    ushort4v u; u[0]=f2bf(v0.x); u[1]=f2bf(v0.y); u[2]=f2bf(v0.z); u[3]=f2bf(v0.w);
    *(ushort4v*)&abuf[0][srow][scol] = u;
  }
  #pragma unroll
  for (int c = 0; c < 8; c++){
    asm volatile("s_waitcnt lgkmcnt(0)" ::: "memory");
    __builtin_amdgcn_s_barrier();
    // B fragments first (wait-for-B leaves the A prefetch outstanding)
    short8 bfr[4];
    #pragma unroll
    for (int ksub = 0; ksub < 4; ksub++)
      bfr[ksub] = *(const short8*)(Bbase + c*128 + ksub*32 + r1*8);
    // depth-2 A prefetch
    float4 nv;
    if (c + 2 < 8) nv = *(const float4*)(srcRow + (c+2)*128);
    // A from LDS + MFMA
    #pragma unroll
    for (int ksub = 0; ksub < 4; ksub++){
      short8 af = *(const short8*)(&abuf[c & 1][r0][ksub*32 + r1*8]);
      acc = __builtin_amdgcn_mfma_f32_16x16x32_bf16(af, bfr[ksub], acc, 0,0,0);
    }
    // stage chunk c+1 into the other buffer
    if (c < 7){
      ushort4v u;
      u[0]=f2bf(v_next.x); u[1]=f2bf(v_next.y); u[2]=f2bf(v_next.z); u[3]=f2bf(v_next.w);
      *(ushort4v*)&abuf[(c+1) & 1][srow][scol] = u;
      v_next = nv;
    }
  }
  // epilogue: D col=lane&15 -> kh_local, row=(lane>>4)*4+r -> s_local
  int kh = wv*16 + r0;
  float qbv = qb[kh];
  int s0 = st*16 + r1*4;
  float4 m = *(const float4*)(mask + b*S_ + s0);
  float4 o;
  o.x = acc[0] + qbv + m.x;
  o.y = acc[1] + qbv + m.y;
  o.z = acc[2] + qbv + m.z;
  o.w = acc[3] + qbv + m.w;
  *(float4*)(scores + ((size_t)(b*KH_) + kh)*S_ + s0) = o;
}

// ---------------- K4: row softmax -> probs bf16 ---------------------------
__global__ __launch_bounds__(256) void k4_softmax(const float* __restrict__ scores,
                                                  ushort* __restrict__ probs){
  __shared__ float red[4];
  int row = blockIdx.x;
  int t = threadIdx.x, wv = t >> 6, lane = t & 63;
  const float* x = scores + (size_t)row * S_;
  float v[8];
  *(float4*)(v)   = *(const float4*)(x + t*8);
  *(float4*)(v+4) = *(const float4*)(x + t*8 + 4);
  float m = v[0];
  #pragma unroll
  for (int i = 1; i < 8; i++) m = fmaxf(m, v[i]);
  #pragma unroll
  for (int off = 32; off; off >>= 1) m = fmaxf(m, __shfl_down(m, off));
  if (lane == 0) red[wv] = m;
  __syncthreads();
  float M = fmaxf(fmaxf(red[0], red[1]), fmaxf(red[2], red[3]));
  __syncthreads();
  float s = 0.f;
  #pragma unroll
  for (int i = 0; i < 8; i++){ v[i] = __expf(v[i] - M); s += v[i]; }
  #pragma unroll
  for (int off = 32; off; off >>= 1) s += __shfl_down(s, off);
  if (lane == 0) red[wv] = s;
  __syncthreads();
  float inv = 1.0f / (red[0] + red[1] + red[2] + red[3]);
  ushort8 o;
  #pragma unroll
  for (int i = 0; i < 8; i++) o[i] = f2bf(v[i] * inv);
  *(ushort8*)(probs + (size_t)row*S_ + t*8) = o;
}

// ---------------- K5: wrepP[sh][b,kh,e] partial = probs·rep (MFMA) --------
// grid 1024: khh=bid&1, sh=(bid>>1)&1, b=(bid>>2)&3, et=bid>>4. 4 waves.
// Batched loads: 8 loads in flight ahead of each 4-MFMA group.
__global__ __launch_bounds__(256) void k5_wrep(const ushort* __restrict__ probs,
                                               const ushort* __restrict__ repT,
                                               float* __restrict__ wrepP){
  int bid = blockIdx.x;
  int khh = bid & 1, sh = (bid >> 1) & 1, b = (bid >> 2) & 3, et = bid >> 4;
  int t = threadIdx.x, wv = t >> 6, lane = t & 63;
  int r0 = lane & 15, r1 = lane >> 4;
  const ushort* Ap = probs + ((size_t)(b*KH_) + khh*64 + wv*16 + r0)*S_ + sh*1024 + r1*8;
  const ushort* Bp = repT  + ((size_t)(b*E_) + et*16 + r0)*S_ + sh*1024 + r1*8;
  f32x4 c = (f32x4){0.f,0.f,0.f,0.f};
  for (int g = 0; g < 8; g++){
    short8 a[4], bb[4];
    #pragma unroll
    for (int j = 0; j < 4; j++){
      a[j]  = *(const short8*)(Ap + (g*4 + j)*32);
      bb[j] = *(const short8*)(Bp + (g*4 + j)*32);
    }
    #pragma unroll
    for (int j = 0; j < 4; j++)
      c = __builtin_amdgcn_mfma_f32_16x16x32_bf16(a[j], bb[j], c, 0,0,0);
  }
  int kh_out = khh*64 + wv*16 + r1*4;
  float* outp = wrepP + (size_t)sh*(B_*KH_*E_)
              + ((size_t)(b*KH_) + kh_out)*E_ + et*16 + r0;
  #pragma unroll
  for (int r = 0; r < 4; r++) outp[(size_t)r*E_] = c[r];
}

// ---------------- K6: ctx[k,b,f] = (wrepP0+wrepP1)[b,kh(f),:]·Wv[k,f,:]+bv
__global__ __launch_bounds__(256) void k6_ctx(const float* __restrict__ wrepP,
                                              const float* __restrict__ Wv,
                                              const float* __restrict__ bv,
                                              float* __restrict__ ctx){
  int gw = (blockIdx.x*256 + threadIdx.x) >> 6;
  int lane = threadIdx.x & 63;
  int k = gw >> 10, f = gw & 1023;
  int h = f >> 6;
  const float* wrow = Wv + ((size_t)(k*E_) + f)*E_;
  const size_t shs = (size_t)B_*KH_*E_;
  float a0=0.f, a1=0.f, a2=0.f, a3=0.f;
  #pragma unroll
  for (int j = 0; j < 4; j++){
    int e = (j*64 + lane)*4;
    float4 w = *(const float4*)(wrow + e);
    #pragma unroll
    for (int b = 0; b < 4; b++){
      const float* xr = wrepP + ((size_t)(b*KH_) + k*16 + h)*E_ + e;
      float4 p0 = *(const float4*)xr;
      float4 p1 = *(const float4*)(xr + shs);
      float s = w.x*(p0.x+p1.x) + w.y*(p0.y+p1.y) + w.z*(p0.z+p1.z) + w.w*(p0.w+p1.w);
      if (b == 0) a0 += s; else if (b == 1) a1 += s; else if (b == 2) a2 += s; else a3 += s;
    }
  }
  #pragma unroll
  for (int off = 32; off; off >>= 1){
    a0 += __shfl_down(a0, off); a1 += __shfl_down(a1, off);
    a2 += __shfl_down(a2, off); a3 += __shfl_down(a3, off);
  }
  if (lane == 0){
    float bvv = bv[k*E_ + f];
    ctx[((size_t)(k*B_) + 0)*E_ + f] = a0 + bvv;
    ctx[((size_t)(k*B_) + 1)*E_ + f] = a1 + bvv;
    ctx[((size_t)(k*B_) + 2)*E_ + f] = a2 + bvv;
    ctx[((size_t)(k*B_) + 3)*E_ + f] = a3 + bvv;
  }
}

// ---------------- K7/K8: out[(k,b),f] = in[(k,b),:]·W[k,f,:] + bias -------
__global__ __launch_bounds__(256) void gemv_kb(const float* __restrict__ in,
                                               const float* __restrict__ W,
                                               const float* __restrict__ bias,
                                               float* __restrict__ outp){
  int gw = (blockIdx.x*256 + threadIdx.x) >> 6;
  int lane = threadIdx.x & 63;
  int k = gw >> 10, f = gw & 1023;
  const float* wrow = W + ((size_t)(k*E_) + f)*E_;
  const float* x0 = in + ((size_t)(k*B_) + 0)*E_;
  const float* x1 = in + ((size_t)(k*B_) + 1)*E_;
  const float* x2 = in + ((size_t)(k*B_) + 2)*E_;
  const float* x3 = in + ((size_t)(k*B_) + 3)*E_;
  float a0=0.f, a1=0.f, a2=0.f, a3=0.f;
  #pragma unroll
  for (int j = 0; j < 4; j++){
    int e = (j*64 + lane)*4;
    float4 w = *(const float4*)(wrow + e);
    float4 p;
    p = *(const float4*)(x0+e); a0 += w.x*p.x + w.y*p.y + w.z*p.z + w.w*p.w;
    p = *(const float4*)(x1+e); a1 += w.x*p.x + w.y*p.y + w.z*p.z + w.w*p.w;
    p = *(const float4*)(x2+e); a2 += w.x*p.x + w.y*p.y + w.z*p.z + w.w*p.w;
    p = *(const float4*)(x3+e); a3 += w.x*p.x + w.y*p.y + w.z*p.z + w.w*p.w;
  }
  #pragma unroll
  for (int off = 32; off; off >>= 1){
    a0 += __shfl_down(a0, off); a1 += __shfl_down(a1, off);
    a2 += __shfl_down(a2, off); a3 += __shfl_down(a3, off);
  }
  if (lane == 0){
    float bb = bias[k*E_ + f];
    outp[((size_t)(k*B_) + 0)*E_ + f] = a0 + bb;
    outp[((size_t)(k*B_) + 1)*E_ + f] = a1 + bb;
    outp[((size_t)(k*B_) + 2)*E_ + f] = a2 + bb;
    outp[((size_t)(k*B_) + 3)*E_ + f] = a3 + bb;
  }
}

// ---------------- K9: LayerNorm over E, write d_out[b,k,e] ----------------
__global__ __launch_bounds__(256) void k9_ln(const float* __restrict__ outkb,
                                             const float* __restrict__ gamma,
                                             const float* __restrict__ beta,
                                             float* __restrict__ out){
  __shared__ float rs[4], rs2[4];
  int row = blockIdx.x;            // b*K_ + k
  int b = row >> 3, k = row & 7;
  int t = threadIdx.x, wv = t >> 6, lane = t & 63;
  const float* x = outkb + ((size_t)(k*B_) + b)*E_;
  float4 v = *(const float4*)(x + t*4);
  float s  = v.x + v.y + v.z + v.w;
  float s2 = v.x*v.x + v.y*v.y + v.z*v.z + v.w*v.w;
  #pragma unroll
  for (int off = 32; off; off >>= 1){ s += __shfl_down(s, off); s2 += __shfl_down(s2, off); }
  if (lane == 0){ rs[wv] = s; rs2[wv] = s2; }
  __syncthreads();
  float S  = rs[0] + rs[1] + rs[2] + rs[3];
  float S2 = rs2[0] + rs2[1] + rs2[2] + rs2[3];
  float mu = S * (1.0f/E_);
  float var = S2 * (1.0f/E_) - mu*mu;
  float inv = rsqrtf(var + 1e-5f);
  float4 g  = *(const float4*)(gamma + t*4);
  float4 bt = *(const float4*)(beta + t*4);
  float4 o;
  o.x = g.x*(v.x-mu)*inv + bt.x;
  o.y = g.y*(v.y-mu)*inv + bt.y;
  o.z = g.z*(v.z-mu)*inv + bt.z;
  o.w = g.w*(v.w-mu)*inv + bt.w;
  *(float4*)(out + ((size_t)(b*K_) + k)*E_ + t*4) = o;
}

extern "C" void kernel_launch(void* const* d_in, const int* in_sizes, int n_in,
                              void* d_out, int out_size, void* d_ws, size_t ws_size,
                              hipStream_t stream){
  const float* rep     = (const float*)d_in[0];
  const float* mask    = (const float*)d_in[1];
  const float* queries = (const float*)d_in[2];
  const float* Wq = (const float*)d_in[3];
  const float* bq = (const float*)d_in[4];
  const float* Wk = (const float*)d_in[5];
  const float* bk = (const float*)d_in[6];
  const float* Wv = (const float*)d_in[7];
  const float* bv = (const float*)d_in[8];
  const float* Wo = (const float*)d_in[9];
  const float* bo = (const float*)d_in[10];
  const float* Wp = (const float*)d_in[11];
  const float* bp = (const float*)d_in[12];
  const float* gamma = (const float*)d_in[13];
  const float* beta  = (const float*)d_in[14];
  float* out = (float*)d_out;

  char* ws = (char*)d_ws;
  size_t off = 0;
  ushort* repT  = (ushort*)(ws + off); off += (size_t)B_*E_*S_*2;      // 16 MB
  float*  qs    = (float*)(ws + off);  off += (size_t)K_*E_*4;         // 32 KB
  ushort* qkb   = (ushort*)(ws + off); off += (size_t)KH_*E_*2;        // 256 KB
  float*  qb    = (float*)(ws + off);  off += 1024;
  float*  scores= (float*)(ws + off);  off += (size_t)B_*KH_*S_*4;     // 4 MB
  ushort* probs = (ushort*)(ws + off); off += (size_t)B_*KH_*S_*2;     // 2 MB
  float*  wrepP = (float*)(ws + off);  off += (size_t)2*B_*KH_*E_*4;   // 4 MB
  float*  ctx   = (float*)(ws + off);  off += (size_t)K_*B_*E_*4;
  float*  attn  = (float*)(ws + off);  off += (size_t)K_*B_*E_*4;
  float*  outkb = (float*)(ws + off);  off += (size_t)K_*B_*E_*4;

  f0_repT_qs<<<4096, 256, 0, stream>>>(rep, repT, queries, Wq, bq, qs);
  k2_qk     <<<512,  256, 0, stream>>>(qs, Wk, bk, qkb, qb);
  k3_scores <<<512,  512, 0, stream>>>(rep, qkb, qb, mask, scores);
  k4_softmax<<<512,  256, 0, stream>>>(scores, probs);
  k5_wrep   <<<1024, 256, 0, stream>>>(probs, repT, wrepP);
  k6_ctx    <<<2048, 256, 0, stream>>>(wrepP, Wv, bv, ctx);
  gemv_kb   <<<2048, 256, 0, stream>>>(ctx, Wo, bo, attn);
  gemv_kb   <<<2048, 256, 0, stream>>>(attn, Wp, bp, outkb);
  k9_ln     <<<32,   256, 0, stream>>>(outkb, gamma, beta, out);
}

// Round 4
// 100.600 us; speedup vs baseline: 1.2818x; 1.1047x over previous
//
#include <hip/hip_runtime.h>
#include <hip/hip_bf16.h>
#include <stdint.h>

#define E_  1024
#define H_  16
#define D_  64
#define K_  8
#define B_  4
#define S_  2048
#define KH_ 128   // K_*H_

typedef __attribute__((ext_vector_type(8))) short   short8;
typedef __attribute__((ext_vector_type(8))) ushort  ushort8;
typedef __attribute__((ext_vector_type(4))) ushort  ushort4v;
typedef __attribute__((ext_vector_type(4))) float   f32x4;

__device__ __forceinline__ ushort f2bf(float x){
  union { float f; uint32_t u; } v; v.f = x;
  return (ushort)((v.u + 0x7FFFu + ((v.u >> 16) & 1u)) >> 16);
}

// ---------------- K1: qs[k,f] = (queries[k,:]·Wq[k,f,:] + bq)*0.125 -------
__global__ __launch_bounds__(256) void k1_qs(const float* __restrict__ queries,
                                             const float* __restrict__ Wq,
                                             const float* __restrict__ bq,
                                             float* __restrict__ qs){
  int gw = (blockIdx.x * 256 + threadIdx.x) >> 6;
  int lane = threadIdx.x & 63;
  int k = gw >> 10, f = gw & 1023;
  const float* wrow = Wq + ((size_t)(k*E_) + f)*E_;
  const float* qrow = queries + k*E_;
  float acc = 0.f;
  #pragma unroll
  for (int j = 0; j < 4; j++){
    int e = (j*64 + lane)*4;
    float4 w = *(const float4*)(wrow + e);
    float4 q = *(const float4*)(qrow + e);
    acc += w.x*q.x + w.y*q.y + w.z*q.z + w.w*q.w;
  }
  #pragma unroll
  for (int off = 32; off; off >>= 1) acc += __shfl_down(acc, off);
  if (lane == 0) qs[k*E_ + f] = (acc + bq[k*E_ + f]) * 0.125f;
}

// ---------------- K2: qk[k,h,e] (bf16) and qb[k,h] ------------------------
__global__ __launch_bounds__(256) void k2_qk(const float* __restrict__ qs,
                                             const float* __restrict__ Wk,
                                             const float* __restrict__ bk,
                                             ushort* __restrict__ qkb,
                                             float* __restrict__ qb){
  int bid = blockIdx.x;
  int eq = bid & 3;
  int kh = bid >> 2;
  int k = kh >> 4, h = kh & 15;
  __shared__ float qsh[64];
  int t = threadIdx.x;
  if (t < 64) qsh[t] = qs[k*E_ + h*64 + t];
  __syncthreads();
  int e = eq*256 + t;
  const float* wbase = Wk + ((size_t)(k*E_) + h*64)*E_ + e;
  float a = 0.f;
  #pragma unroll 8
  for (int d = 0; d < 64; d++) a += qsh[d] * wbase[(size_t)d*E_];
  qkb[kh*E_ + e] = f2bf(a);
  if (eq == 0 && t == 0){
    float s = 0.f;
    for (int d = 0; d < 64; d++) s += qsh[d] * bk[k*E_ + h*64 + d];
    qb[kh] = s;
  }
}

// ---------------- K3: scores[b,kh,s] = rep·qk + qb + mask -----------------
// 512 blocks = b(4) x st(128 tiles of 16 s). 512 threads = 8 waves.
// Double-buffered LDS A-tile; depth-2 reg prefetch of the f32 staging loads;
// B-frag (qkb/L2) loads pipelined one chunk ahead; raw s_barrier (no vmcnt
// drain) keeps everything in flight.
#define K3PAD 8
__global__ __launch_bounds__(512) void k3_scores(const float* __restrict__ rep,
                                                 const ushort* __restrict__ qkb,
                                                 const float* __restrict__ qb,
                                                 const float* __restrict__ mask,
                                                 float* __restrict__ scores){
  __shared__ __align__(16) ushort abuf[2][16][128 + K3PAD];
  int bid = blockIdx.x;
  int st = bid & 127;
  int b  = bid >> 7;
  int t = threadIdx.x, wv = t >> 6, lane = t & 63;
  int r0 = lane & 15, r1 = lane >> 4;
  int srow = t >> 5;           // 0..15
  int scol = (t & 31) * 4;     // 0..124
  const float* srcRow = rep + ((size_t)(b*S_) + st*16 + srow)*E_ + scol;
  const ushort* Bbase = qkb + ((size_t)(wv*16) + r0)*E_;
  f32x4 acc = (f32x4){0.f,0.f,0.f,0.f};

  // prologue: chunk0+chunk1 A-loads in flight; chunk0 B-frags in flight
  float4 v0     = *(const float4*)(srcRow);
  float4 v_next = *(const float4*)(srcRow + 128);
  short8 bfr[4], bnx[4];
  #pragma unroll
  for (int ksub = 0; ksub < 4; ksub++)
    bfr[ksub] = *(const short8*)(Bbase + ksub*32 + r1*8);
  {
    ushort4v u; u[0]=f2bf(v0.x); u[1]=f2bf(v0.y); u[2]=f2bf(v0.z); u[3]=f2bf(v0.w);
    *(ushort4v*)&abuf[0][srow][scol] = u;
  }
  #pragma unroll
  for (int c = 0; c < 8; c++){
    asm volatile("s_waitcnt lgkmcnt(0)" ::: "memory");
    __builtin_amdgcn_s_barrier();
    // next chunk's B-frags (used next iteration)
    if (c < 7){
      #pragma unroll
      for (int ksub = 0; ksub < 4; ksub++)
        bnx[ksub] = *(const short8*)(Bbase + (c+1)*128 + ksub*32 + r1*8);
    }
    // depth-2 A prefetch
    float4 nv;
    if (c + 2 < 8) nv = *(const float4*)(srcRow + (c+2)*128);
    // A from LDS + MFMA (uses bfr loaded last iteration)
    #pragma unroll
    for (int ksub = 0; ksub < 4; ksub++){
      short8 af = *(const short8*)(&abuf[c & 1][r0][ksub*32 + r1*8]);
      acc = __builtin_amdgcn_mfma_f32_16x16x32_bf16(af, bfr[ksub], acc, 0,0,0);
    }
    if (c < 7){
      ushort4v u;
      u[0]=f2bf(v_next.x); u[1]=f2bf(v_next.y); u[2]=f2bf(v_next.z); u[3]=f2bf(v_next.w);
      *(ushort4v*)&abuf[(c+1) & 1][srow][scol] = u;
      v_next = nv;
      #pragma unroll
      for (int ksub = 0; ksub < 4; ksub++) bfr[ksub] = bnx[ksub];
    }
  }
  int kh = wv*16 + r0;
  float qbv = qb[kh];
  int s0 = st*16 + r1*4;
  float4 m = *(const float4*)(mask + b*S_ + s0);
  float4 o;
  o.x = acc[0] + qbv + m.x;
  o.y = acc[1] + qbv + m.y;
  o.z = acc[2] + qbv + m.z;
  o.w = acc[3] + qbv + m.w;
  *(float4*)(scores + ((size_t)(b*KH_) + kh)*S_ + s0) = o;
}

// ---------------- K4: row softmax -> probs bf16 ---------------------------
__global__ __launch_bounds__(256) void k4_softmax(const float* __restrict__ scores,
                                                  ushort* __restrict__ probs){
  __shared__ float red[4];
  int row = blockIdx.x;
  int t = threadIdx.x, wv = t >> 6, lane = t & 63;
  const float* x = scores + (size_t)row * S_;
  float v[8];
  *(float4*)(v)   = *(const float4*)(x + t*8);
  *(float4*)(v+4) = *(const float4*)(x + t*8 + 4);
  float m = v[0];
  #pragma unroll
  for (int i = 1; i < 8; i++) m = fmaxf(m, v[i]);
  #pragma unroll
  for (int off = 32; off; off >>= 1) m = fmaxf(m, __shfl_down(m, off));
  if (lane == 0) red[wv] = m;
  __syncthreads();
  float M = fmaxf(fmaxf(red[0], red[1]), fmaxf(red[2], red[3]));
  __syncthreads();
  float s = 0.f;
  #pragma unroll
  for (int i = 0; i < 8; i++){ v[i] = __expf(v[i] - M); s += v[i]; }
  #pragma unroll
  for (int off = 32; off; off >>= 1) s += __shfl_down(s, off);
  if (lane == 0) red[wv] = s;
  __syncthreads();
  float inv = 1.0f / (red[0] + red[1] + red[2] + red[3]);
  ushort8 o;
  #pragma unroll
  for (int i = 0; i < 8; i++) o[i] = f2bf(v[i] * inv);
  *(ushort8*)(probs + (size_t)row*S_ + t*8) = o;
}

// ---------------- K5: wrepP[sp][b,kh,e] = probs·rep (direct rep, LDS^T) ---
// 256 blocks: sp=bid&3 (512-s), b=(bid>>2)&3, et=bid>>4 (64-e). 512 thr.
// Wave w: e-sub (w&3)*16, kh-half (w>>2)*64 (4 m-tiles of 16).
// LDS bt[e][s'] bf16, pitch 40 u16 (80B, 16B-aligned rows); s' = s XOR-swz.
#define K5P 40
__global__ __launch_bounds__(512) void k5_wrep(const ushort* __restrict__ probs,
                                               const float* __restrict__ rep,
                                               float* __restrict__ wrepP){
  __shared__ __align__(16) ushort bt[2][64*K5P];
  int bid = blockIdx.x;
  int sp = bid & 3, b = (bid>>2) & 3, et = bid >> 4;
  int t = threadIdx.x, w = t >> 6, lane = t & 63;
  int r0 = lane & 15, r1 = lane >> 4;
  int we = (w & 3) * 16;
  int khh = (w >> 2) * 64;
  int s0 = sp * 512;
  // staging role: ss = s-row 0..31, e4 = 4-e chunk
  int ss = t >> 4, e4 = (t & 15) * 4;
  const float* src = rep + ((size_t)(b*S_) + s0 + ss)*E_ + et*64 + e4;
  const ushort* Ab = probs + ((size_t)(b*KH_) + khh + r0)*S_ + s0 + r1*8;
  f32x4 acc[4];
  #pragma unroll
  for (int mt = 0; mt < 4; mt++) acc[mt] = (f32x4){0.f,0.f,0.f,0.f};

  // prologue: tile0 staged; tile0 A-frags in flight
  float4 pv = *(const float4*)src;
  short8 Ac[4], An[4];
  #pragma unroll
  for (int mt = 0; mt < 4; mt++)
    Ac[mt] = *(const short8*)(Ab + (size_t)(mt*16)*S_);
  {
    float vv[4] = {pv.x, pv.y, pv.z, pv.w};
    #pragma unroll
    for (int i = 0; i < 4; i++){
      int e = e4 + i;
      int swz = ss ^ (((e >> 3) & 3) << 3);
      bt[0][e*K5P + swz] = f2bf(vv[i]);
    }
  }
  #pragma unroll
  for (int tile = 0; tile < 16; tile++){
    int cur = tile & 1;
    float4 nv;
    if (tile < 15){
      nv = *(const float4*)(src + (size_t)(tile+1)*32*E_);
      #pragma unroll
      for (int mt = 0; mt < 4; mt++)
        An[mt] = *(const short8*)(Ab + (size_t)(mt*16)*S_ + (tile+1)*32);
    }
    asm volatile("s_waitcnt lgkmcnt(0)" ::: "memory");
    __builtin_amdgcn_s_barrier();
    // B-frag: row e_loc, s-chunk r1*8 (swizzled), single ds_read_b128
    int e_loc = we + r0;
    int swz = (r1*8) ^ (((e_loc >> 3) & 3) << 3);
    short8 bf = *(const short8*)&bt[cur][e_loc*K5P + swz];
    #pragma unroll
    for (int mt = 0; mt < 4; mt++)
      acc[mt] = __builtin_amdgcn_mfma_f32_16x16x32_bf16(Ac[mt], bf, acc[mt], 0,0,0);
    if (tile < 15){
      float vv[4] = {nv.x, nv.y, nv.z, nv.w};
      #pragma unroll
      for (int i = 0; i < 4; i++){
        int e = e4 + i;
        int sw2 = ss ^ (((e >> 3) & 3) << 3);
        bt[cur ^ 1][e*K5P + sw2] = f2bf(vv[i]);
      }
      #pragma unroll
      for (int mt = 0; mt < 4; mt++) Ac[mt] = An[mt];
    }
  }
  // epilogue: C col=lane&15 -> e, row=(lane>>4)*4+r -> kh
  int eo = et*64 + we + r0;
  float* op = wrepP + (size_t)sp*((size_t)B_*KH_*E_) + ((size_t)(b*KH_))*E_ + eo;
  #pragma unroll
  for (int mt = 0; mt < 4; mt++){
    int khq = khh + mt*16 + r1*4;
    #pragma unroll
    for (int r = 0; r < 4; r++)
      op[(size_t)(khq + r)*E_] = acc[mt][r];
  }
}

// ---------------- K6: ctx[k,b,f] = (Σ_sp wrepP)[b,kh(f),:]·Wv[k,f,:]+bv ---
__global__ __launch_bounds__(256) void k6_ctx(const float* __restrict__ wrepP,
                                              const float* __restrict__ Wv,
                                              const float* __restrict__ bv,
                                              float* __restrict__ ctx){
  int gw = (blockIdx.x*256 + threadIdx.x) >> 6;
  int lane = threadIdx.x & 63;
  int k = gw >> 10, f = gw & 1023;
  int h = f >> 6;
  const float* wrow = Wv + ((size_t)(k*E_) + f)*E_;
  const size_t shs = (size_t)B_*KH_*E_;
  float a0=0.f, a1=0.f, a2=0.f, a3=0.f;
  #pragma unroll
  for (int j = 0; j < 4; j++){
    int e = (j*64 + lane)*4;
    float4 wv4 = *(const float4*)(wrow + e);
    #pragma unroll
    for (int b = 0; b < 4; b++){
      const float* xr = wrepP + ((size_t)(b*KH_) + k*16 + h)*E_ + e;
      float4 p0 = *(const float4*)xr;
      float4 p1 = *(const float4*)(xr + shs);
      float4 p2 = *(const float4*)(xr + 2*shs);
      float4 p3 = *(const float4*)(xr + 3*shs);
      float sx = wv4.x*(p0.x+p1.x+p2.x+p3.x) + wv4.y*(p0.y+p1.y+p2.y+p3.y)
               + wv4.z*(p0.z+p1.z+p2.z+p3.z) + wv4.w*(p0.w+p1.w+p2.w+p3.w);
      if (b == 0) a0 += sx; else if (b == 1) a1 += sx; else if (b == 2) a2 += sx; else a3 += sx;
    }
  }
  #pragma unroll
  for (int off = 32; off; off >>= 1){
    a0 += __shfl_down(a0, off); a1 += __shfl_down(a1, off);
    a2 += __shfl_down(a2, off); a3 += __shfl_down(a3, off);
  }
  if (lane == 0){
    float bvv = bv[k*E_ + f];
    ctx[((size_t)(k*B_) + 0)*E_ + f] = a0 + bvv;
    ctx[((size_t)(k*B_) + 1)*E_ + f] = a1 + bvv;
    ctx[((size_t)(k*B_) + 2)*E_ + f] = a2 + bvv;
    ctx[((size_t)(k*B_) + 3)*E_ + f] = a3 + bvv;
  }
}

// ---------------- K7/K8: out[(k,b),f] = in[(k,b),:]·W[k,f,:] + bias -------
__global__ __launch_bounds__(256) void gemv_kb(const float* __restrict__ in,
                                               const float* __restrict__ W,
                                               const float* __restrict__ bias,
                                               float* __restrict__ outp){
  int gw = (blockIdx.x*256 + threadIdx.x) >> 6;
  int lane = threadIdx.x & 63;
  int k = gw >> 10, f = gw & 1023;
  const float* wrow = W + ((size_t)(k*E_) + f)*E_;
  const float* x0 = in + ((size_t)(k*B_) + 0)*E_;
  const float* x1 = in + ((size_t)(k*B_) + 1)*E_;
  const float* x2 = in + ((size_t)(k*B_) + 2)*E_;
  const float* x3 = in + ((size_t)(k*B_) + 3)*E_;
  float a0=0.f, a1=0.f, a2=0.f, a3=0.f;
  #pragma unroll
  for (int j = 0; j < 4; j++){
    int e = (j*64 + lane)*4;
    float4 w = *(const float4*)(wrow + e);
    float4 p;
    p = *(const float4*)(x0+e); a0 += w.x*p.x + w.y*p.y + w.z*p.z + w.w*p.w;
    p = *(const float4*)(x1+e); a1 += w.x*p.x + w.y*p.y + w.z*p.z + w.w*p.w;
    p = *(const float4*)(x2+e); a2 += w.x*p.x + w.y*p.y + w.z*p.z + w.w*p.w;
    p = *(const float4*)(x3+e); a3 += w.x*p.x + w.y*p.y + w.z*p.z + w.w*p.w;
  }
  #pragma unroll
  for (int off = 32; off; off >>= 1){
    a0 += __shfl_down(a0, off); a1 += __shfl_down(a1, off);
    a2 += __shfl_down(a2, off); a3 += __shfl_down(a3, off);
  }
  if (lane == 0){
    float bb = bias[k*E_ + f];
    outp[((size_t)(k*B_) + 0)*E_ + f] = a0 + bb;
    outp[((size_t)(k*B_) + 1)*E_ + f] = a1 + bb;
    outp[((size_t)(k*B_) + 2)*E_ + f] = a2 + bb;
    outp[((size_t)(k*B_) + 3)*E_ + f] = a3 + bb;
  }
}

// ---------------- K9: LayerNorm over E, write d_out[b,k,e] ----------------
__global__ __launch_bounds__(256) void k9_ln(const float* __restrict__ outkb,
                                             const float* __restrict__ gamma,
                                             const float* __restrict__ beta,
                                             float* __restrict__ out){
  __shared__ float rs[4], rs2[4];
  int row = blockIdx.x;            // b*K_ + k
  int b = row >> 3, k = row & 7;
  int t = threadIdx.x, wv = t >> 6, lane = t & 63;
  const float* x = outkb + ((size_t)(k*B_) + b)*E_;
  float4 v = *(const float4*)(x + t*4);
  float s  = v.x + v.y + v.z + v.w;
  float s2 = v.x*v.x + v.y*v.y + v.z*v.z + v.w*v.w;
  #pragma unroll
  for (int off = 32; off; off >>= 1){ s += __shfl_down(s, off); s2 += __shfl_down(s2, off); }
  if (lane == 0){ rs[wv] = s; rs2[wv] = s2; }
  __syncthreads();
  float S  = rs[0] + rs[1] + rs[2] + rs[3];
  float S2 = rs2[0] + rs2[1] + rs2[2] + rs2[3];
  float mu = S * (1.0f/E_);
  float var = S2 * (1.0f/E_) - mu*mu;
  float inv = rsqrtf(var + 1e-5f);
  float4 g  = *(const float4*)(gamma + t*4);
  float4 bt = *(const float4*)(beta + t*4);
  float4 o;
  o.x = g.x*(v.x-mu)*inv + bt.x;
  o.y = g.y*(v.y-mu)*inv + bt.y;
  o.z = g.z*(v.z-mu)*inv + bt.z;
  o.w = g.w*(v.w-mu)*inv + bt.w;
  *(float4*)(out + ((size_t)(b*K_) + k)*E_ + t*4) = o;
}

extern "C" void kernel_launch(void* const* d_in, const int* in_sizes, int n_in,
                              void* d_out, int out_size, void* d_ws, size_t ws_size,
                              hipStream_t stream){
  const float* rep     = (const float*)d_in[0];
  const float* mask    = (const float*)d_in[1];
  const float* queries = (const float*)d_in[2];
  const float* Wq = (const float*)d_in[3];
  const float* bq = (const float*)d_in[4];
  const float* Wk = (const float*)d_in[5];
  const float* bk = (const float*)d_in[6];
  const float* Wv = (const float*)d_in[7];
  const float* bv = (const float*)d_in[8];
  const float* Wo = (const float*)d_in[9];
  const float* bo = (const float*)d_in[10];
  const float* Wp = (const float*)d_in[11];
  const float* bp = (const float*)d_in[12];
  const float* gamma = (const float*)d_in[13];
  const float* beta  = (const float*)d_in[14];
  float* out = (float*)d_out;

  char* ws = (char*)d_ws;
  size_t off = 0;
  float*  qs    = (float*)(ws + off);  off += (size_t)K_*E_*4;         // 32 KB
  ushort* qkb   = (ushort*)(ws + off); off += (size_t)KH_*E_*2;        // 256 KB
  float*  qb    = (float*)(ws + off);  off += 1024;
  float*  scores= (float*)(ws + off);  off += (size_t)B_*KH_*S_*4;     // 4 MB
  ushort* probs = (ushort*)(ws + off); off += (size_t)B_*KH_*S_*2;     // 2 MB
  float*  wrepP = (float*)(ws + off);  off += (size_t)4*B_*KH_*E_*4;   // 8 MB
  float*  ctx   = (float*)(ws + off);  off += (size_t)K_*B_*E_*4;
  float*  attn  = (float*)(ws + off);  off += (size_t)K_*B_*E_*4;
  float*  outkb = (float*)(ws + off);  off += (size_t)K_*B_*E_*4;

  k1_qs     <<<2048, 256, 0, stream>>>(queries, Wq, bq, qs);
  k2_qk     <<<512,  256, 0, stream>>>(qs, Wk, bk, qkb, qb);
  k3_scores <<<512,  512, 0, stream>>>(rep, qkb, qb, mask, scores);
  k4_softmax<<<512,  256, 0, stream>>>(scores, probs);
  k5_wrep   <<<256,  512, 0, stream>>>(probs, rep, wrepP);
  k6_ctx    <<<2048, 256, 0, stream>>>(wrepP, Wv, bv, ctx);
  gemv_kb   <<<2048, 256, 0, stream>>>(ctx, Wo, bo, attn);
  gemv_kb   <<<2048, 256, 0, stream>>>(attn, Wp, bp, outkb);
  k9_ln     <<<32,   256, 0, stream>>>(outkb, gamma, beta, out);
}